// Round 15
// baseline (77.118 us; speedup 1.0000x reference)
//
#include <hip/hip_runtime.h>
#include <math.h>

namespace {

constexpr int   MTOT = 4096;       // total nodes
constexpr float H    = 0.1f;

// W_FACTORS = sqrt((0.5^2 + sigma^2)/2), sigma in {0.4, 0.8, 1.2, 1.6}
constexpr float W0 = 0.45276925690687087f;
constexpr float W1 = 0.66708320320631664f;
constexpr float W2 = 0.91923881554251174f;
constexpr float W3 = 1.18532695911296985f;

constexpr float KCOUL   = 14.399645478425669f;  // e*1e10/eps0/(4*pi)
constexpr float HALF_L1 = 2.8867513459481287f;  // 0.5*sqrt(3)/0.3
constexpr float SQRTPI  = 1.7724538509055159f;
constexpr float TWOSQPI = 1.1283791670955126f;  // 2/sqrt(pi)

// k_r = 0.5/W_r
constexpr float K0 = 1.1043153f, K1 = 0.74953184f, K2 = 0.54392830f, K3 = 0.42182454f;

// epilogue erf (A&S 7.1.25, |err|<=2.5e-5): pk=0.47047*k, c2=-k^2*log2e
constexpr float PK0 = 0.5195472f, PK1 = 0.3526314f, PK2 = 0.2559019f, PK3 = 0.1984558f;
constexpr float C20 = -1.7593842f, C21 = -0.8105028f, C22 = -0.4268329f, C23 = -0.2567073f;
constexpr float EA1 = 0.3480242f, EA2 = -0.0958798f, EA3 = 0.7478556f;
constexpr float RCP_H = 9.9999000f, RCP_HS2 = 7.0710178f, RCP_2H = 4.9999750f;

// erf lookup table (exact near path): 512 entries, h = 0.015, d in [0, 7.68)
constexpr int   TABN  = 512;
constexpr float TAB_H = 0.015f;
constexpr float INV_H = 66.666664f;

// g/Gt tables (main loop): 256 entries, h = 0.03, d in [0, 7.68)
constexpr int   TGN   = 256;
constexpr float TG_H  = 0.03f;
constexpr float INV_G = 33.333332f;

// exact-correction radius: any lane with center distance < 2
constexpr float NEAR2 = 4.0f;

__device__ __forceinline__ float fast_rcp(float x)  { return __builtin_amdgcn_rcpf(x); }
__device__ __forceinline__ float fast_rsq(float x)  { return __builtin_amdgcn_rsqf(x); }
__device__ __forceinline__ float fast_exp2(float x) { return __builtin_amdgcn_exp2f(x); }

// epilogue: q = erfc-part of A&S 7.1.25
__device__ __forceinline__ float erf_q(float d, float d2, float pk, float c2) {
  float t = fast_rcp(__builtin_fmaf(d, pk, 1.0f));
  float poly = t * __builtin_fmaf(t, __builtin_fmaf(t, EA3, EA2), EA1);
  return poly * fast_exp2(d2 * c2);
}

// g(d) = erf(kd)/d ; Gt(d) = 0.2*(erf/d^3 - (2k/sqrt(pi)) e^{-k^2 d^2}/d^2).
// Both smooth/bounded on [0,inf). Series for d<0.5 (closed form cancels catastrophically).
__device__ __forceinline__ float g_of(float k, float d) {
  const float k2d2 = k * k * d * d;
  if (d < 0.5f)
    return TWOSQPI * k * (1.0f - k2d2 * (1.0f / 3.0f) + k2d2 * k2d2 * 0.1f);
  return erff(k * d) / d;
}
__device__ __forceinline__ float gt_of(float k, float d) {
  const float k2d2 = k * k * d * d;
  if (d < 0.5f)
    return 0.2f * TWOSQPI * k * k * k *
           (2.0f / 3.0f - 0.4f * k2d2 + k2d2 * k2d2 * (1.0f / 7.0f));
  const float e = erff(k * d), x = expf(-k2d2);
  return 0.2f * e / (d * d * d) - 0.2f * TWOSQPI * k * x / (d * d);
}

// project (7 x 4) site-features S[j*4+r] -> 16 outputs
__device__ __forceinline__ float project_one(const float* S, int k) {
  if (k < 4) return S[k];
  int q = k - 4;
  int r = q / 3;
  int comp = q - 3 * r;
  int j1, j2;
  if (comp == 0)      { j1 = 2; j2 = 5; }
  else if (comp == 1) { j1 = 3; j2 = 6; }
  else                { j1 = 1; j2 = 4; }
  return HALF_L1 * (S[j1 * 4 + r] - S[j2 * 4 + r]);
}

__device__ __forceinline__ unsigned spread3(int v) {
  return (unsigned)((v & 1) | ((v & 2) << 2) | ((v & 4) << 4));
}

// grid: 256 blocks = 32 graphs x 8 node-blocks; block: 896 thr = 112 sites x 8 chunks.
// Loop 1: branchless monopole+dipole for ALL sources. Loop 2: exact 7-site
// correction (subtract mid, add exact) for near sources only (wave-uniform mask).
__global__ __launch_bounds__(896, 4) void es_main(
    const float* __restrict__ sf,   // (4096, 4)
    const float* __restrict__ pos,  // (4096, 3)
    float* __restrict__ out)        // [0:65536) features, [65536:131072) self_terms
{
  __shared__ float4   s_pos4[128];     // node centers (SORTED)
  __shared__ float4   s_chg4[128];     // prescaled charges {s0,5s3,5s1,5s2} (SORTED)
  __shared__ int      s_orig[128];     // sorted slot -> original node
  __shared__ unsigned s_key[128];
  __shared__ float4   s_tabV[TABN];    // erf values (r0..r3)
  __shared__ float4   s_tabD[TABN];    // erf per-cell deltas
  __shared__ float4   s_gV[TGN], s_gD[TGN];   // g value+delta
  __shared__ float4   s_tV[TGN], s_tD[TGN];   // Gt value+delta
  __shared__ __align__(16) char s_u[8 * 112 * 16];  // union: erf raw build | s_part
  __shared__ float    s_feat[448];
  __shared__ float    s_self[448];

  float (*s_tmp)[TABN + 1] = reinterpret_cast<float (*)[TABN + 1]>(s_u);  // [4][513]
  float4* s_part = reinterpret_cast<float4*>(s_u);                        // [8*112]

  const int b   = blockIdx.x;
  const int g   = b >> 3;    // graph
  const int nb  = b & 7;     // node-block (sorted space)
  const int tid = threadIdx.x;

  // ---- phase 1: node data + keys; erf raw; g/Gt tables ----
  float px = 0.f, py = 0.f, pz = 0.f;
  float4 myc = make_float4(0.f, 0.f, 0.f, 0.f);
  if (tid < 128) {
    const float* p = pos + (size_t)(g * 128 + tid) * 3;
    px = p[0]; py = p[1]; pz = p[2];
    const float4 s = ((const float4*)sf)[g * 128 + tid];
    myc = make_float4(s.x, 5.0f * s.w, 5.0f * s.y, 5.0f * s.z);
    int cx = (int)((px + 16.0f) * 0.25f); cx = (cx < 0) ? 0 : (cx > 7 ? 7 : cx);
    int cy = (int)((py + 16.0f) * 0.25f); cy = (cy < 0) ? 0 : (cy > 7 ? 7 : cy);
    int cz = (int)((pz + 16.0f) * 0.25f); cz = (cz < 0) ? 0 : (cz > 7 ? 7 : cz);
    unsigned mort = spread3(cx) | (spread3(cy) << 1) | (spread3(cz) << 2);
    s_key[tid] = (mort << 7) | (unsigned)tid;
  }
  if (tid <= TABN) {
    const float d = tid * TAB_H;
    s_tmp[0][tid] = erff(K0 * d);
    s_tmp[1][tid] = erff(K1 * d);
    s_tmp[2][tid] = erff(K2 * d);
    s_tmp[3][tid] = erff(K3 * d);
  }
  if (tid >= 640) {                      // 256 threads build g/Gt tables
    const int e = tid - 640;             // 0..255
    const float d0 = e * TG_H;
    const float d1 = (e + 1) * TG_H;
    const float ks[4] = {K0, K1, K2, K3};
    float gv[4], gd[4], tv[4], td[4];
#pragma unroll
    for (int r = 0; r < 4; ++r) {
      const float k = ks[r];
      const float g0 = g_of(k, d0),  g1 = g_of(k, d1);
      const float t0 = gt_of(k, d0), t1 = gt_of(k, d1);
      gv[r] = g0; gd[r] = g1 - g0; tv[r] = t0; td[r] = t1 - t0;
    }
    s_gV[e] = make_float4(gv[0], gv[1], gv[2], gv[3]);
    s_gD[e] = make_float4(gd[0], gd[1], gd[2], gd[3]);
    s_tV[e] = make_float4(tv[0], tv[1], tv[2], tv[3]);
    s_tD[e] = make_float4(td[0], td[1], td[2], td[3]);
  }
  __syncthreads();

  // ---- phase 2: rank-sort scatter; pack erf tables ----
  if (tid < 128) {
    const unsigned mykey = s_key[tid];
    int rank = 0;
    for (int t = 0; t < 128; ++t) rank += (s_key[t] < mykey) ? 1 : 0;
    s_pos4[rank] = make_float4(px, py, pz, 0.0f);
    s_chg4[rank] = myc;
    s_orig[rank] = tid;
  }
  if (tid < TABN) {
    const float v0 = s_tmp[0][tid], v1 = s_tmp[1][tid];
    const float v2v = s_tmp[2][tid], v3 = s_tmp[3][tid];
    s_tabV[tid] = make_float4(v0, v1, v2v, v3);
    s_tabD[tid] = make_float4(s_tmp[0][tid + 1] - v0, s_tmp[1][tid + 1] - v1,
                              s_tmp[2][tid + 1] - v2v, s_tmp[3][tid + 1] - v3);
  }
  __syncthreads();

  // ---- per-thread target site (sorted space) ----
  const int site_local = tid % 112;
  const int chunk      = tid / 112;          // 0..7, 16 source nodes each
  const int sl   = nb * 112 + site_local;
  const int jown = (sl * 9363) >> 16;        // own node slot
  const int aoff = sl - jown * 7;

  const float4 cp = s_pos4[jown];
  const float tx = cp.x + ((aoff == 1) ? H : (aoff == 4) ? -H : 0.0f);
  const float ty = cp.y + ((aoff == 2) ? H : (aoff == 5) ? -H : 0.0f);
  const float tz = cp.z + ((aoff == 3) ? H : (aoff == 6) ? -H : 0.0f);

  float a0 = 0.f, a1 = 0.f, a2 = 0.f, a3 = 0.f;

  // monopole+dipole contribution of source node j (valid at ALL distances;
  // identical arithmetic in loop 1 and loop 2 so the subtraction cancels).
  auto mid_contrib = [&](int j, float& v2raw) -> float4 {
    const float4 p4 = s_pos4[j];
    const float4 c4 = s_chg4[j];
    const float vx = tx - p4.x;
    const float vy = ty - p4.y;
    const float vz = tz - p4.z;
    const float v2r = __builtin_fmaf(vx, vx, __builtin_fmaf(vy, vy, vz * vz));
    v2raw = v2r;
    const float v2 = fmaxf(v2r, 1e-6f);      // own-center pair: d=1e-3, tables smooth there
    const float rd = fast_rsq(v2);
    const float d  = v2 * rd;
    const float dot = __builtin_fmaf(c4.y, vx, __builtin_fmaf(c4.z, vy, c4.w * vz));
    const float t   = d * INV_G;
    const int   idx = (int)t;
    const bool  in  = (idx < TGN - 1);
    const int   ic  = in ? idx : (TGN - 2);
    const float f   = fminf(t - (float)idx, 1.0f);
    const float4 Gv = s_gV[ic], Gd = s_gD[ic];
    const float4 Tv = s_tV[ic], Td = s_tD[ic];
    const float gs  = rd;                    // saturated g = 1/d
    const float ts  = 0.2f * rd * rd * rd;   // saturated Gt = 0.2/d^3
    const float g0v = in ? __builtin_fmaf(Gd.x, f, Gv.x) : gs;
    const float g1v = in ? __builtin_fmaf(Gd.y, f, Gv.y) : gs;
    const float g2v = in ? __builtin_fmaf(Gd.z, f, Gv.z) : gs;
    const float g3v = in ? __builtin_fmaf(Gd.w, f, Gv.w) : gs;
    const float t0v = in ? __builtin_fmaf(Td.x, f, Tv.x) : ts;
    const float t1v = in ? __builtin_fmaf(Td.y, f, Tv.y) : ts;
    const float t2v = in ? __builtin_fmaf(Td.z, f, Tv.z) : ts;
    const float t3v = in ? __builtin_fmaf(Td.w, f, Tv.w) : ts;
    return make_float4(__builtin_fmaf(c4.x, g0v, dot * t0v),
                       __builtin_fmaf(c4.x, g1v, dot * t1v),
                       __builtin_fmaf(c4.x, g2v, dot * t2v),
                       __builtin_fmaf(c4.x, g3v, dot * t3v));
  };

  auto acc_full = [&](float d2raw, float c) {
    float d2 = fmaxf(d2raw, 1e-12f);
    float rd = fast_rsq(d2);
    float cv = c * rd;
    float t  = (d2 * rd) * INV_H;
    int  idx = (int)t;
    float f  = t - (float)idx;
    idx = (idx < TABN - 1) ? idx : (TABN - 1);
    f = fminf(f, 1.0f);
    const float4 V = s_tabV[idx];
    const float4 D = s_tabD[idx];
    a0 = __builtin_fmaf(cv, __builtin_fmaf(D.x, f, V.x), a0);
    a1 = __builtin_fmaf(cv, __builtin_fmaf(D.y, f, V.y), a1);
    a2 = __builtin_fmaf(cv, __builtin_fmaf(D.z, f, V.z), a2);
    a3 = __builtin_fmaf(cv, __builtin_fmaf(D.w, f, V.w), a3);
  };

  const int j0 = chunk * 16;

  // ---- loop 1: branchless monopole+dipole over all 16 sources ----
  unsigned nearmask = 0;
#pragma unroll 4
  for (int jj = 0; jj < 16; ++jj) {
    float v2r;
    const float4 r = mid_contrib(j0 + jj, v2r);
    a0 += r.x; a1 += r.y; a2 += r.z; a3 += r.w;
    if (__any(v2r < NEAR2)) nearmask |= (1u << jj);
  }

  // ---- loop 2: exact correction for near sources (wave-uniform mask walk) ----
  while (nearmask) {
    const int jj = __ffs(nearmask) - 1;
    nearmask &= nearmask - 1;
    const int j = j0 + jj;
    float v2r;
    const float4 r = mid_contrib(j, v2r);      // identical arithmetic -> cancels
    a0 -= r.x; a1 -= r.y; a2 -= r.z; a3 -= r.w;
    const float4 p4 = s_pos4[j];
    const float4 c4 = s_chg4[j];
    const float vx = tx - p4.x;
    const float vy = ty - p4.y;
    const float vz = tz - p4.z;
    const float v2 = __builtin_fmaf(vx, vx, __builtin_fmaf(vy, vy, vz * vz));
    const float w2 = v2 + 0.01f;
    const bool own = (j == jown);
    acc_full(v2,                            (own & (aoff == 0)) ? 0.0f :  c4.x);
    acc_full(__builtin_fmaf(vx, -0.2f, w2), (own & (aoff == 1)) ? 0.0f :  c4.y);
    acc_full(__builtin_fmaf(vy, -0.2f, w2), (own & (aoff == 2)) ? 0.0f :  c4.z);
    acc_full(__builtin_fmaf(vz, -0.2f, w2), (own & (aoff == 3)) ? 0.0f :  c4.w);
    acc_full(__builtin_fmaf(vx,  0.2f, w2), (own & (aoff == 4)) ? 0.0f : -c4.y);
    acc_full(__builtin_fmaf(vy,  0.2f, w2), (own & (aoff == 5)) ? 0.0f : -c4.z);
    acc_full(__builtin_fmaf(vz,  0.2f, w2), (own & (aoff == 6)) ? 0.0f : -c4.w);
  }

  s_part[chunk * 112 + site_local] = make_float4(a0, a1, a2, a3);
  __syncthreads();

  // ---- reduce chunks + self term + own-node correction (cancels to +c_a*diag) ----
  if (tid < 448) {
    const int site = tid >> 2;   // 0..111 (sorted space)
    const int r    = tid & 3;
    const float* pf = (const float*)s_part;
    float tot = 0.f;
#pragma unroll
    for (int c = 0; c < 8; ++c) tot += pf[c * 448 + tid];

    const float w  = (r == 0) ? W0  : (r == 1) ? W1  : (r == 2) ? W2  : W3;
    const float pk = (r == 0) ? PK0 : (r == 1) ? PK1 : (r == 2) ? PK2 : PK3;
    const float c2 = (r == 0) ? C20 : (r == 1) ? C21 : (r == 2) ? C22 : C23;
    const float diag = fast_rcp(w * SQRTPI);
    const float ph1 = (1.f - erf_q(0.1f,        0.01f, pk, c2)) * RCP_H;
    const float ph2 = (1.f - erf_q(0.14142136f, 0.02f, pk, c2)) * RCP_HS2;
    const float ph3 = (1.f - erf_q(0.2f,        0.04f, pk, c2)) * RCP_2H;

    const int jn = (site * 9363) >> 16;
    const int ba = site - jn * 7;
    const float4 c4 = s_chg4[nb * 16 + jn];
    float selfSum = 0.f, ca = 0.f;
#pragma unroll
    for (int i = 0; i < 7; ++i) {
      const float ci = (i == 0) ?  c4.x : (i == 1) ?  c4.y : (i == 2) ?  c4.z :
                       (i == 3) ?  c4.w : (i == 4) ? -c4.y : (i == 5) ? -c4.z : -c4.w;
      float ph;
      if (i == ba)                             ph = diag;
      else if (i == 0 || ba == 0)              ph = ph1;
      else if ((i - ba == 3) || (ba - i == 3)) ph = ph3;
      else                                     ph = ph2;
      selfSum = __builtin_fmaf(ci, ph, selfSum);
      if (i == ba) ca = ci;
    }
    s_self[tid] = KCOUL * selfSum;
    s_feat[tid] = KCOUL * __builtin_fmaf(ca, diag, tot);
  }
  __syncthreads();

  // ---- projection + write (map sorted node -> original id) ----
  if (tid < 256) {
    const int node = tid >> 4;
    const int k    = tid & 15;
    const int m    = g * 128 + s_orig[nb * 16 + node];
    float vf = project_one(&s_feat[node * 28], k);
    float vs = project_one(&s_self[node * 28], k);
    out[m * 16 + k]             = vf;
    out[MTOT * 16 + m * 16 + k] = vs;
  }
}

} // namespace

extern "C" void kernel_launch(void* const* d_in, const int* in_sizes, int n_in,
                              void* d_out, int out_size, void* d_ws, size_t ws_size,
                              hipStream_t stream) {
  const float* sf  = (const float*)d_in[0];   // source_feats (4096,1,4)
  const float* pos = (const float*)d_in[1];   // node_positions (4096,3)
  float* out = (float*)d_out;
  es_main<<<256, 896, 0, stream>>>(sf, pos, out);
}